// Round 1
// 1053.383 us; speedup vs baseline: 3.0733x; 3.0733x over previous
//
#include <hip/hip_runtime.h>
#include <math.h>

typedef __attribute__((ext_vector_type(8))) short bf16x8;
typedef __attribute__((ext_vector_type(4))) float f32x4;

// ---------------- workspace layout ----------------
// ushort region (bf16 packed weights), offsets in ushorts:
#define UOFF_CAW 0L        // conv A  [l8][mp4][tap9][ic4][split2][mt2][lane64][e8] = 2359296 bf16
#define UOFF_FAW 2359296L  // fusion A [l8][fm2 8][ic4][split2][mt2][lane64][e8]   =  524288 bf16
#define UOFF_H1W 2883584L  // h1 A [blk2][mp8][slab8][ic4][split2][mt2][lane64][e8]= 1048576 bf16
#define NB_TOT   3932160L  // total bf16 elems (= 1966080 floats)
// float region, offsets in floats:
#define OFF_W1G  1966080L  // [c256][o512] = 131072
#define OFF_W2S  2097152L  // [wv16][i256][o8] = 32768
#define OFF_GRAW 2129920L  // [512][256] = 131072
#define OFF_HG   2260992L  // [512][512] = 262144
#define OFF_DYN  2523136L  // states (granules, 131072 f/poly) + h1 (65536 f/poly)
#define REPACK_N 4096000L  // NB_TOT + 131072 + 32768

// ---------------- helpers ----------------
__device__ inline ushort f2bf_rne(float x) {
  uint u = __float_as_uint(x);
  return (ushort)((u + 0x7FFFu + ((u >> 16) & 1u)) >> 16);
}
__device__ inline void split_bf(float x, ushort& h, ushort& l) {
  uint u = __float_as_uint(x);
  uint hb = (u + 0x7FFFu + ((u >> 16) & 1u)) & 0xFFFF0000u;
  h = (ushort)(hb >> 16);
  l = f2bf_rne(x - __uint_as_float(hb));
}
__device__ inline ushort bfsel(float w, int split) {
  uint u = __float_as_uint(w);
  uint hb = (u + 0x7FFFu + ((u >> 16) & 1u)) & 0xFFFF0000u;
  if (split == 0) return (ushort)(hb >> 16);
  float lo = w - __uint_as_float(hb);
  uint ul = __float_as_uint(lo);
  return (ushort)((ul + 0x7FFFu + ((ul >> 16) & 1u)) >> 16);
}
__device__ inline bf16x8 mkb(uint a, uint b, uint c, uint d) {
  union { uint u[4]; bf16x8 v; } x; x.u[0] = a; x.u[1] = b; x.u[2] = c; x.u[3] = d; return x.v;
}
__device__ inline bf16x8 asb(uint4 a) {
  union { uint4 u; bf16x8 v; } x; x.u = a; return x.v;
}
__device__ inline f32x4 MFMA_(bf16x8 a, bf16x8 b, f32x4 c) {
  return __builtin_amdgcn_mfma_f32_16x16x32_bf16(a, b, c, 0, 0, 0);
}
__device__ inline uint4 packg(const ushort* h, const ushort* l) {
  uint4 p;
  p.x = (uint)h[0] | ((uint)h[1] << 16); p.y = (uint)h[2] | ((uint)h[3] << 16);
  p.z = (uint)l[0] | ((uint)l[1] << 16); p.w = (uint)l[2] | ((uint)l[3] << 16);
  return p;
}

// ---------------- repack: split weights to bf16 hi/lo in MFMA fragment order ----------------
__global__ void k_repack(const float* __restrict__ head_w, const float* __restrict__ res_w,
                         const float* __restrict__ fusion_w,
                         const float* __restrict__ pred1_w, const float* __restrict__ cls1_w,
                         const float* __restrict__ pred2_w, const float* __restrict__ cls2_w,
                         float* __restrict__ ws) {
  const long j = (long)blockIdx.x * 256 + threadIdx.x;
  if (j >= REPACK_N) return;
  if (j < NB_TOT) {
    ushort* wsu = (ushort*)ws;
    float w;
    if (j < UOFF_FAW) {                       // CAW
      int e = (int)(j & 7); long q = j >> 3;
      int lane = (int)(q & 63); q >>= 6;
      int mt = (int)(q & 1); q >>= 1;
      int split = (int)(q & 1); q >>= 1;
      int ic = (int)(q & 3); q >>= 2;
      int tap = (int)(q % 9); q /= 9;
      int mp = (int)(q & 3); int l = (int)(q >> 2);
      int gg = lane >> 4;
      int kl = (e < 4) ? (4 * gg + e) : (16 + 4 * gg + e - 4);
      int m = mp * 32 + mt * 16 + (lane & 15);
      int i = ic * 32 + kl;
      if (l == 0) w = (i < 67) ? head_w[((long)m * 67 + i) * 9 + tap] : 0.f;
      else        w = res_w[(((long)(l - 1) * 128 + m) * 128 + i) * 9 + tap];
      wsu[j] = bfsel(w, split);
    } else if (j < UOFF_H1W) {                // FAW
      long jj = j - UOFF_FAW;
      int e = (int)(jj & 7); long q = jj >> 3;
      int lane = (int)(q & 63); q >>= 6;
      int mt = (int)(q & 1); q >>= 1;
      int split = (int)(q & 1); q >>= 1;
      int ic = (int)(q & 3); q >>= 2;
      int fm2 = (int)(q & 7); int l = (int)(q >> 3);
      int gg = lane >> 4;
      int kl = (e < 4) ? (4 * gg + e) : (16 + 4 * gg + e - 4);
      int m = fm2 * 32 + mt * 16 + (lane & 15);
      int i = ic * 32 + kl;
      w = fusion_w[(long)m * 1024 + l * 128 + i];
      wsu[j] = bfsel(w, split);
    } else {                                  // H1W
      long jj = j - UOFF_H1W;
      int e = (int)(jj & 7); long q = jj >> 3;
      int lane = (int)(q & 63); q >>= 6;
      int mt = (int)(q & 1); q >>= 1;
      int split = (int)(q & 1); q >>= 1;
      int ic = (int)(q & 3); q >>= 2;
      int slab = (int)(q & 7); q >>= 3;
      int mp = (int)(q & 7); int blk = (int)(q >> 3);
      int gg = lane >> 4;
      int kl = (e < 4) ? (4 * gg + e) : (16 + 4 * gg + e - 4);
      int m = blk * 256 + mp * 32 + mt * 16 + (lane & 15);
      int k = slab * 128 + ic * 32 + kl;
      w = (m < 256) ? pred1_w[(long)m * 1280 + 256 + k] : cls1_w[(long)(m - 256) * 1280 + 256 + k];
      wsu[j] = bfsel(w, split);
    }
  } else if (j < NB_TOT + 131072) {           // W1G (fp32)
    long q = j - NB_TOT; int o = (int)(q & 511); int c = (int)(q >> 9);
    ws[OFF_W1G + q] = (o < 256) ? pred1_w[(long)o * 1280 + c] : cls1_w[(long)(o - 256) * 1280 + c];
  } else {                                    // W2S (fp32)
    long q = j - NB_TOT - 131072;
    int o = (int)(q & 7); int i = (int)((q >> 3) & 255); int wvv = (int)(q >> 11);
    int jg = wvv * 8 + o;
    ws[OFF_W2S + q] = (jg < 64) ? pred2_w[jg * 256 + i] : cls2_w[(jg - 64) * 256 + i];
  }
}

// ================ K1: gather + 8-layer conv chain (MFMA) + incremental fusion (MFMA) ================
// LDS x-tile: per position p, 32 granules of 16B = [hi bf16 x4][lo bf16 x4] for channels 4g..4g+3,
// granule swizzled: grp' = grp ^ (p&7)  -> stride-512B column reads are bank-conflict-free.
__global__ __launch_bounds__(1024)
void k_conv(const float* __restrict__ cnn, const float* __restrict__ i_it,
            const float* __restrict__ c_it, const float* __restrict__ cls_in,
            const int* __restrict__ ind,
            const ushort* __restrict__ CAW, const ushort* __restrict__ FAW,
            const float* __restrict__ head_b, const float* __restrict__ res_b,
            float* __restrict__ graw, float* __restrict__ states, int p0) {
  __shared__ ushort xt[32768];   // 64 KB: [p 128][granule 32][8 ushort]
  __shared__ float scr[512];
  const int ln = blockIdx.x, n = p0 + ln, t = threadIdx.x;
  const int lane = t & 63, li = lane & 15, g = lane >> 4;
  const int wv = __builtin_amdgcn_readfirstlane(t >> 6);
  const int mp = wv & 3, np = wv >> 2;     // conv: 2 m-tiles x 2 n-tiles per wave
  const int fm2 = wv & 7, fq = wv >> 3;    // fusion: 2 m-tiles x 4 n-tiles per wave

  // ---- bilinear gather -> LDS granules ----
  {
    const int p = t & 127, qg = t >> 7;    // qg wave-uniform (2 waves per qg)
    const long nb = (long)n * 128 + p;
    uint4 pk[4];
    if (qg < 4) {
      const float gx = i_it[nb * 2 + 0] - 0.5f;
      const float gy = i_it[nb * 2 + 1] - 0.5f;
      const float fx = floorf(gx), fy = floorf(gy);
      const float wx = gx - fx, wy = gy - fy;
      const int x0 = (int)fx, y0 = (int)fy, x1 = x0 + 1, y1 = y0 + 1;
      const bool vx0 = (x0 >= 0) & (x0 < 128), vx1 = (x1 >= 0) & (x1 < 128);
      const bool vy0 = (y0 >= 0) & (y0 < 128), vy1 = (y1 >= 0) & (y1 < 128);
      const int x0c = min(max(x0, 0), 127), x1c = min(max(x1, 0), 127);
      const int y0c = min(max(y0, 0), 127), y1c = min(max(y1, 0), 127);
      const float w00 = (vx0 && vy0) ? (1.f - wx) * (1.f - wy) : 0.f;
      const float w01 = (vx1 && vy0) ? wx * (1.f - wy) : 0.f;
      const float w10 = (vx0 && vy1) ? (1.f - wx) * wy : 0.f;
      const float w11 = (vx1 && vy1) ? wx * wy : 0.f;
      const long base = (long)ind[n] * (64L * 16384);
      const int a00 = y0c * 128 + x0c, a01 = y0c * 128 + x1c;
      const int a10 = y1c * 128 + x0c, a11 = y1c * 128 + x1c;
#pragma unroll
      for (int qq = 0; qq < 4; qq++) {
        ushort hh[4], ll[4];
#pragma unroll
        for (int cc = 0; cc < 4; cc++) {
          const int c = qg * 16 + qq * 4 + cc;
          const float* f = cnn + base + (long)c * 16384;
          float x = f[a00] * w00 + f[a01] * w01 + f[a10] * w10 + f[a11] * w11;
          split_bf(x, hh[cc], ll[cc]);
        }
        pk[qq] = packg(hh, ll);
      }
    } else if (qg == 4) {
      float v0 = c_it[nb * 2 + 0] * 4.f, v1 = c_it[nb * 2 + 1] * 4.f, v2 = cls_in[nb];
      ushort hh[4], ll[4];
      split_bf(v0, hh[0], ll[0]); split_bf(v1, hh[1], ll[1]); split_bf(v2, hh[2], ll[2]);
      hh[3] = 0; ll[3] = 0;
      pk[0] = packg(hh, ll);
      pk[1] = make_uint4(0, 0, 0, 0); pk[2] = make_uint4(0, 0, 0, 0); pk[3] = make_uint4(0, 0, 0, 0);
    } else {
      pk[0] = make_uint4(0, 0, 0, 0); pk[1] = make_uint4(0, 0, 0, 0);
      pk[2] = make_uint4(0, 0, 0, 0); pk[3] = make_uint4(0, 0, 0, 0);
    }
#pragma unroll
    for (int qq = 0; qq < 4; qq++) {
      const int grp = qg * 4 + qq;
      *(uint4*)&xt[p * 256 + ((grp ^ (p & 7)) << 3)] = pk[qq];
    }
  }
  __syncthreads();

  const f32x4 fz = {0.f, 0.f, 0.f, 0.f};
  f32x4 facc[2][4];
#pragma unroll
  for (int a = 0; a < 2; a++)
#pragma unroll
    for (int b = 0; b < 4; b++) facc[a][b] = fz;

  const uint4* caw = (const uint4*)CAW;
  const uint4* faw = (const uint4*)FAW;
  uint4* stp = (uint4*)(states + (long)ln * 131072);

  for (int l = 0; l < 8; l++) {
    const int dil = (l >= 6) ? 4 : ((l >= 4) ? 2 : 1);
    f32x4 cacc[2][2];
    cacc[0][0] = fz; cacc[0][1] = fz; cacc[1][0] = fz; cacc[1][1] = fz;
    const uint4* cawl = caw + (l * 4 + mp) * 9216;
    for (int tap = 0; tap < 9; tap++) {
      const int shift = (tap - 4) * dil;
      int ua0, ua1;
      {
        const int pc0 = (np * 32 + li + shift + 128) & 127;
        ua0 = pc0 * 256 + ((g ^ (pc0 & 7)) << 3);
        const int pc1 = (np * 32 + 16 + li + shift + 128) & 127;
        ua1 = pc1 * 256 + ((g ^ (pc1 & 7)) << 3);
      }
      const uint4* cawt = cawl + tap * 1024 + lane;
#pragma unroll
      for (int ic = 0; ic < 4; ic++) {
        const uint4 ah0 = cawt[ic * 256 + 0];
        const uint4 ah1 = cawt[ic * 256 + 64];
        const uint4 al0 = cawt[ic * 256 + 128];
        const uint4 al1 = cawt[ic * 256 + 192];
        const uint4 r0a = *(const uint4*)&xt[ua0 + ic * 64];
        const uint4 r0b = *(const uint4*)&xt[(ua0 + ic * 64) ^ 32];
        const uint4 r1a = *(const uint4*)&xt[ua1 + ic * 64];
        const uint4 r1b = *(const uint4*)&xt[(ua1 + ic * 64) ^ 32];
        const bf16x8 bh0 = mkb(r0a.x, r0a.y, r0b.x, r0b.y);
        const bf16x8 bl0 = mkb(r0a.z, r0a.w, r0b.z, r0b.w);
        const bf16x8 bh1 = mkb(r1a.x, r1a.y, r1b.x, r1b.y);
        const bf16x8 bl1 = mkb(r1a.z, r1a.w, r1b.z, r1b.w);
        const bf16x8 Ah0 = asb(ah0), Ah1 = asb(ah1), Al0 = asb(al0), Al1 = asb(al1);
        cacc[0][0] = MFMA_(Ah0, bh0, cacc[0][0]);
        cacc[0][1] = MFMA_(Ah0, bh1, cacc[0][1]);
        cacc[1][0] = MFMA_(Ah1, bh0, cacc[1][0]);
        cacc[1][1] = MFMA_(Ah1, bh1, cacc[1][1]);
        cacc[0][0] = MFMA_(Ah0, bl0, cacc[0][0]);
        cacc[0][1] = MFMA_(Ah0, bl1, cacc[0][1]);
        cacc[1][0] = MFMA_(Ah1, bl0, cacc[1][0]);
        cacc[1][1] = MFMA_(Ah1, bl1, cacc[1][1]);
        cacc[0][0] = MFMA_(Al0, bh0, cacc[0][0]);
        cacc[0][1] = MFMA_(Al0, bh1, cacc[0][1]);
        cacc[1][0] = MFMA_(Al1, bh0, cacc[1][0]);
        cacc[1][1] = MFMA_(Al1, bh1, cacc[1][1]);
      }
    }
    __syncthreads();
    // ---- bias + relu + residual, write back LDS granules + states granules ----
    {
      const float* bsrc = (l == 0) ? head_b : (res_b + (l - 1) * 128);
#pragma unroll
      for (int mt = 0; mt < 2; mt++) {
        const int grp_o = mp * 8 + mt * 4 + g;
        const float4 bias = *(const float4*)&bsrc[grp_o * 4];
#pragma unroll
        for (int nt = 0; nt < 2; nt++) {
          const int p = np * 32 + nt * 16 + li;
          const int ux = p * 256 + ((grp_o ^ (p & 7)) << 3);
          float v0 = fmaxf(cacc[mt][nt][0] + bias.x, 0.f);
          float v1 = fmaxf(cacc[mt][nt][1] + bias.y, 0.f);
          float v2 = fmaxf(cacc[mt][nt][2] + bias.z, 0.f);
          float v3 = fmaxf(cacc[mt][nt][3] + bias.w, 0.f);
          if (l > 0) {
            const uint4 old = *(const uint4*)&xt[ux];
            v0 += __uint_as_float((old.x & 0xFFFFu) << 16) + __uint_as_float((old.z & 0xFFFFu) << 16);
            v1 += __uint_as_float(old.x & 0xFFFF0000u) + __uint_as_float(old.z & 0xFFFF0000u);
            v2 += __uint_as_float((old.y & 0xFFFFu) << 16) + __uint_as_float((old.w & 0xFFFFu) << 16);
            v3 += __uint_as_float(old.y & 0xFFFF0000u) + __uint_as_float(old.w & 0xFFFF0000u);
          }
          ushort hh[4], ll[4];
          split_bf(v0, hh[0], ll[0]); split_bf(v1, hh[1], ll[1]);
          split_bf(v2, hh[2], ll[2]); split_bf(v3, hh[3], ll[3]);
          const uint4 pk = packg(hh, ll);
          *(uint4*)&xt[ux] = pk;
          stp[(l * 32 + grp_o) * 128 + p] = pk;   // states granules [l][grp][p]
        }
      }
    }
    __syncthreads();
    // ---- incremental fusion for slot l (MFMA) ----
    {
      const uint4* fawl = faw + (l * 8 + fm2) * 1024 + lane;
#pragma unroll
      for (int ic = 0; ic < 4; ic++) {
        const uint4 ah0 = fawl[ic * 256 + 0];
        const uint4 ah1 = fawl[ic * 256 + 64];
        const uint4 al0 = fawl[ic * 256 + 128];
        const uint4 al1 = fawl[ic * 256 + 192];
        const bf16x8 Ah0 = asb(ah0), Ah1 = asb(ah1), Al0 = asb(al0), Al1 = asb(al1);
#pragma unroll
        for (int nt = 0; nt < 4; nt++) {
          const int pc = fq * 64 + nt * 16 + li;
          const int ub = pc * 256 + ((g ^ (pc & 7)) << 3) + ic * 64;
          const uint4 ra = *(const uint4*)&xt[ub];
          const uint4 rb = *(const uint4*)&xt[ub ^ 32];
          const bf16x8 bh = mkb(ra.x, ra.y, rb.x, rb.y);
          const bf16x8 bl = mkb(ra.z, ra.w, rb.z, rb.w);
          facc[0][nt] = MFMA_(Ah0, bh, facc[0][nt]);
          facc[1][nt] = MFMA_(Ah1, bh, facc[1][nt]);
          facc[0][nt] = MFMA_(Ah0, bl, facc[0][nt]);
          facc[1][nt] = MFMA_(Ah1, bl, facc[1][nt]);
          facc[0][nt] = MFMA_(Al0, bh, facc[0][nt]);
          facc[1][nt] = MFMA_(Al1, bh, facc[1][nt]);
        }
      }
    }
  }

  // ---- fusion row-max over 128 positions -> graw ----
#pragma unroll
  for (int mt = 0; mt < 2; mt++) {
#pragma unroll
    for (int r = 0; r < 4; r++) {
      float m = fmaxf(fmaxf(facc[mt][0][r], facc[mt][1][r]),
                      fmaxf(facc[mt][2][r], facc[mt][3][r]));
#pragma unroll
      for (int s = 1; s < 16; s <<= 1) m = fmaxf(m, __shfl_xor(m, s, 64));
      if (li == 0) scr[(fm2 * 32 + mt * 16 + g * 4 + r) * 2 + fq] = m;
    }
  }
  __syncthreads();
  if (t < 256) graw[(long)n * 256 + t] = fmaxf(scr[2 * t], scr[2 * t + 1]);
}

// =============== K_hg: hg[n][o] = bias + W1G[:,o].(graw+fus_b) (unchanged) ===============
__global__ __launch_bounds__(512)
void k_hg(const float* __restrict__ graw, const float* __restrict__ fus_b,
          const float* __restrict__ W1G, const float* __restrict__ p1b, const float* __restrict__ c1b,
          float* __restrict__ hg, int p0) {
  __shared__ float sg[256];
  const int n = p0 + blockIdx.x, t = threadIdx.x;
  if (t < 256) sg[t] = graw[(long)n * 256 + t] + fus_b[t];
  __syncthreads();
  float s = (t < 256) ? p1b[t] : c1b[t - 256];
  const float* w = W1G + t;
#pragma unroll 8
  for (int c = 0; c < 256; c++) s = fmaf(w[(long)c * 512], sg[c], s);
  hg[(long)n * 512 + t] = s;
}

// =============== K2: h1 = relu(W1H @ states + hg), MFMA, 2 blocks/poly ===============
__global__ __launch_bounds__(1024)
void k_h1(const float* __restrict__ states, const ushort* __restrict__ H1W,
          const float* __restrict__ hg, float* __restrict__ h1, int p0) {
  __shared__ ushort xt[32768];
  const int b = blockIdx.x, ln = b >> 1, blk = b & 1, t = threadIdx.x;
  const int n = p0 + ln;
  const int lane = t & 63, li = lane & 15, g = lane >> 4;
  const int wv = __builtin_amdgcn_readfirstlane(t >> 6);
  const int mp = wv & 7, q = wv >> 3;
  const uint4* sp = (const uint4*)(states + (long)ln * 131072);
  const uint4* aw = (const uint4*)H1W;
  const f32x4 fz = {0.f, 0.f, 0.f, 0.f};
  f32x4 acc[2][4];
#pragma unroll
  for (int a = 0; a < 2; a++)
#pragma unroll
    for (int c = 0; c < 4; c++) acc[a][c] = fz;

  for (int slab = 0; slab < 8; slab++) {
    if (slab) __syncthreads();
#pragma unroll
    for (int k = 0; k < 4; k++) {
      const int gi = k * 1024 + t;
      const int grp = gi >> 7, p = gi & 127;
      const uint4 v = sp[slab * 4096 + gi];
      *(uint4*)&xt[p * 256 + ((grp ^ (p & 7)) << 3)] = v;
    }
    __syncthreads();
    const uint4* awl = aw + ((blk * 8 + mp) * 8 + slab) * 1024 + lane;
#pragma unroll
    for (int ic = 0; ic < 4; ic++) {
      const uint4 ah0 = awl[ic * 256 + 0];
      const uint4 ah1 = awl[ic * 256 + 64];
      const uint4 al0 = awl[ic * 256 + 128];
      const uint4 al1 = awl[ic * 256 + 192];
      const bf16x8 Ah0 = asb(ah0), Ah1 = asb(ah1), Al0 = asb(al0), Al1 = asb(al1);
#pragma unroll
      for (int nt = 0; nt < 4; nt++) {
        const int pc = q * 64 + nt * 16 + li;
        const int ub = pc * 256 + ((g ^ (pc & 7)) << 3) + ic * 64;
        const uint4 ra = *(const uint4*)&xt[ub];
        const uint4 rb = *(const uint4*)&xt[ub ^ 32];
        const bf16x8 bh = mkb(ra.x, ra.y, rb.x, rb.y);
        const bf16x8 bl = mkb(ra.z, ra.w, rb.z, rb.w);
        acc[0][nt] = MFMA_(Ah0, bh, acc[0][nt]);
        acc[1][nt] = MFMA_(Ah1, bh, acc[1][nt]);
        acc[0][nt] = MFMA_(Ah0, bl, acc[0][nt]);
        acc[1][nt] = MFMA_(Ah1, bl, acc[1][nt]);
        acc[0][nt] = MFMA_(Al0, bh, acc[0][nt]);
        acc[1][nt] = MFMA_(Al1, bh, acc[1][nt]);
      }
    }
  }
  const float* hgp = hg + (long)n * 512;
  float* hb = h1 + (long)ln * 65536;
#pragma unroll
  for (int mt = 0; mt < 2; mt++) {
    const int ob = blk * 256 + mp * 32 + mt * 16 + g * 4;
    const float4 hq = *(const float4*)&hgp[ob];
#pragma unroll
    for (int nt = 0; nt < 4; nt++) {
      const int p = q * 64 + nt * 16 + li;
      float* d = hb + (long)ob * 128 + p;
      d[0]   = fmaxf(acc[mt][nt][0] + hq.x, 0.f);
      d[128] = fmaxf(acc[mt][nt][1] + hq.y, 0.f);
      d[256] = fmaxf(acc[mt][nt][2] + hq.z, 0.f);
      d[384] = fmaxf(acc[mt][nt][3] + hq.w, 0.f);
    }
  }
}

// =============== K3: pred2/cls2 + pred3/cls3 + outputs + NMS (unchanged) ===============
__global__ __launch_bounds__(1024) __attribute__((amdgpu_waves_per_eu(4)))
void k_tail(const float* __restrict__ h1, const float* __restrict__ W2S,
            const float* __restrict__ p2b, const float* __restrict__ c2b,
            const float* __restrict__ p3w, const float* __restrict__ p3b,
            const float* __restrict__ c3w, const float* __restrict__ c3b,
            const float* __restrict__ i_it, float* __restrict__ out, int p0) {
  __shared__ float h2[16384];
  __shared__ float xb[2048], xc[2048];
  const int ln = blockIdx.x, n = p0 + ln, t = threadIdx.x;
  const int po = t & 63;
  const int wv = __builtin_amdgcn_readfirstlane(t >> 6);
  const float* h1p = h1 + (long)ln * 65536;
  const float* wbase = W2S + (long)wv * 2048;
  float a0[8], a1[8];
#pragma unroll
  for (int jj = 0; jj < 8; jj++) { a0[jj] = 0.f; a1[jj] = 0.f; }
  for (int c = 0; c < 16; c++) {
    __syncthreads();
    ((float2*)xb)[t] = ((const float2*)(h1p + (long)c * 2048))[t];
    ((float2*)xc)[t] = ((const float2*)(h1p + 32768 + (long)c * 2048))[t];
    __syncthreads();
    const float* xp = (wv < 8) ? xb : xc;
    const float* wc = wbase + c * 128;
#pragma unroll 4
    for (int i = 0; i < 16; i++) {
      const float xv0 = xp[i * 128 + po];
      const float xv1 = xp[i * 128 + po + 64];
      const float* w = wc + i * 8;
#pragma unroll
      for (int jj = 0; jj < 8; jj++) {
        a0[jj] = fmaf(w[jj], xv0, a0[jj]);
        a1[jj] = fmaf(w[jj], xv1, a1[jj]);
      }
    }
  }
#pragma unroll
  for (int jj = 0; jj < 8; jj++) {
    const int j = wv * 8 + jj;
    const float bb = (j < 64) ? p2b[j] : c2b[j - 64];
    h2[j * 128 + po] = fmaxf(a0[jj] + bb, 0.f);
    h2[j * 128 + po + 64] = fmaxf(a1[jj] + bb, 0.f);
  }
  __syncthreads();

  float sig = 0.f;
  const int pp = t & 127;
  if (t < 128) {
    float o0v = p3b[0], o1v = p3b[1], cv = c3b[0];
    for (int j = 0; j < 64; j++) {
      const float hp = h2[j * 128 + pp];
      const float hc = h2[(64 + j) * 128 + pp];
      o0v = fmaf(p3w[j], hp, o0v);
      o1v = fmaf(p3w[64 + j], hp, o1v);
      cv = fmaf(c3w[j], hc, cv);
    }
    const long ip = ((long)n * 128 + pp) * 2;
    out[ip + 0] = i_it[ip + 0] * 4.f + o0v;
    out[ip + 1] = i_it[ip + 1] * 4.f + o1v;
    out[131072 + (long)n * 128 + pp] = cv;
    sig = 1.f / (1.f + expf(-cv));
  }
  __syncthreads();
  if (t < 128) xb[pp] = sig;
  __syncthreads();
  if (t < 128) {
    float m = xb[pp];
#pragma unroll
    for (int s = 1; s <= 2; s++) {
      m = fmaxf(m, xb[(pp + s) & 127]);
      m = fmaxf(m, xb[(pp + 128 - s) & 127]);
    }
    out[196608 + (long)n * 128 + pp] = (sig >= m) ? sig : 0.f;
  }
}

extern "C" void kernel_launch(void* const* d_in, const int* in_sizes, int n_in,
                              void* d_out, int out_size, void* d_ws, size_t ws_size,
                              hipStream_t stream) {
  const float* cnn      = (const float*)d_in[0];
  const float* i_it     = (const float*)d_in[1];
  const float* c_it     = (const float*)d_in[2];
  const float* it_cls   = (const float*)d_in[3];
  const int*   ind      = (const int*)d_in[4];
  const float* head_w   = (const float*)d_in[5];
  const float* head_b   = (const float*)d_in[6];
  const float* res_w    = (const float*)d_in[7];
  const float* res_b    = (const float*)d_in[8];
  const float* fusion_w = (const float*)d_in[9];
  const float* fusion_b = (const float*)d_in[10];
  const float* pred1_w  = (const float*)d_in[11];
  const float* pred1_b  = (const float*)d_in[12];
  const float* pred2_w  = (const float*)d_in[13];
  const float* pred2_b  = (const float*)d_in[14];
  const float* pred3_w  = (const float*)d_in[15];
  const float* pred3_b  = (const float*)d_in[16];
  const float* cls1_w   = (const float*)d_in[17];
  const float* cls1_b   = (const float*)d_in[18];
  const float* cls2_w   = (const float*)d_in[19];
  const float* cls2_b   = (const float*)d_in[20];
  const float* cls3_w   = (const float*)d_in[21];
  const float* cls3_b   = (const float*)d_in[22];
  float* ws = (float*)d_ws;
  float* out = (float*)d_out;
  const ushort* wsu = (const ushort*)d_ws;

  k_repack<<<(int)((REPACK_N + 255) / 256), 256, 0, stream>>>(
      head_w, res_w, fusion_w, pred1_w, cls1_w, pred2_w, cls2_w, ws);

  long avail_f = (long)(ws_size / 4) - OFF_DYN;
  long Cl = avail_f / 196608;
  int C = (Cl >= 512) ? 512 : ((Cl >= 256) ? 256 : (int)(Cl < 1 ? 1 : Cl));
  float* states = ws + OFF_DYN;
  float* h1 = states + (long)C * 131072;

  for (int p0 = 0; p0 < 512; p0 += C) {
    int Cc = (512 - p0 < C) ? (512 - p0) : C;
    k_conv<<<Cc, 1024, 0, stream>>>(cnn, i_it, c_it, it_cls, ind,
                                    wsu + UOFF_CAW, wsu + UOFF_FAW, head_b, res_b,
                                    ws + OFF_GRAW, states, p0);
    k_hg<<<Cc, 512, 0, stream>>>(ws + OFF_GRAW, fusion_b, ws + OFF_W1G,
                                 pred1_b, cls1_b, ws + OFF_HG, p0);
    k_h1<<<2 * Cc, 1024, 0, stream>>>(states, wsu + UOFF_H1W, ws + OFF_HG, h1, p0);
    k_tail<<<Cc, 1024, 0, stream>>>(h1, ws + OFF_W2S, pred2_b, cls2_b,
                                    pred3_w, pred3_b, cls3_w, cls3_b,
                                    i_it, out, p0);
  }
}